// Round 7
// baseline (55.803 us; speedup 1.0000x reference)
//
#include <hip/hip_runtime.h>

#define K_SEGS 8192
#define ALPHA_W 0.5f
#define NEG_INF_BITS 0xFF800000
#define LDS_CAP 64            // id window per block (chunk spans ~5 ids; 64 = 12x margin)
#define NBLOCKS 2048
#define BLOCK 256

// ---------------------------------------------------------------------------
// Kernel 0: init global accumulators (ws poisoned 0xAA once, never re-poisoned)
// ---------------------------------------------------------------------------
__global__ void init_ws_kernel(float* __restrict__ seg_sum,
                               int* __restrict__ seg_max_bits) {
    int k = blockIdx.x * blockDim.x + threadIdx.x;
    if (k < K_SEGS) {
        seg_sum[k] = 0.0f;
        seg_max_bits[k] = (int)NEG_INF_BITS;  // node_loss >= 0 so signed-int max ordering valid
    }
}

// ---------------------------------------------------------------------------
// focal loss for one node given its 8 logits + target
// ---------------------------------------------------------------------------
__device__ __forceinline__ float node_focal(float4 a, float4 b, int t) {
    float x0 = a.x, x1 = a.y, x2 = a.z, x3 = a.w;
    float x4 = b.x, x5 = b.y, x6 = b.z, x7 = b.w;
    float m = fmaxf(fmaxf(fmaxf(x0, x1), fmaxf(x2, x3)),
                    fmaxf(fmaxf(x4, x5), fmaxf(x6, x7)));
    float s = __expf(x0 - m) + __expf(x1 - m) + __expf(x2 - m) + __expf(x3 - m)
            + __expf(x4 - m) + __expf(x5 - m) + __expf(x6 - m) + __expf(x7 - m);
    float lse = __logf(s) + m;
    float xt;
    switch (t) {
        case 0: xt = x0; break; case 1: xt = x1; break;
        case 2: xt = x2; break; case 3: xt = x3; break;
        case 4: xt = x4; break; case 5: xt = x5; break;
        case 6: xt = x6; break; default: xt = x7; break;
    }
    float ce = lse - xt;              // >= 0
    float pt = __expf(-ce);           // (0, 1]
    float om = 1.0f - pt;
    return om * om * ce;              // >= 0
}

// ---------------------------------------------------------------------------
// Kernel 1: 2 nodes/thread, LDS-privatized segmented sum/max (sorted cid)
// Each block owns a CONTIGUOUS node chunk -> narrow id window.
// ---------------------------------------------------------------------------
__global__ __launch_bounds__(BLOCK) void node_loss_kernel(
        const float* __restrict__ logits,   // [N, 8]
        const int* __restrict__ targets,    // [N]
        const int* __restrict__ cid,        // [N], sorted
        float* __restrict__ seg_sum,        // [K]
        int* __restrict__ seg_max_bits,     // [K]
        int n) {
    __shared__ float lsum[LDS_CAP];
    __shared__ int   lmax[LDS_CAP];

    const int tid  = threadIdx.x;
    const int lane = tid & 63;

    const int chunk  = (n + NBLOCKS - 1) / NBLOCKS;   // even (1954) for N=4M
    const int cstart = blockIdx.x * chunk;
    if (cstart >= n) return;                          // whole block exits together
    const int cend = min(cstart + chunk, n);
    const int base = cid[cstart];                     // broadcast load

    for (int j = tid; j < LDS_CAP; j += BLOCK) {
        lsum[j] = 0.0f;
        lmax[j] = (int)NEG_INF_BITS;
    }
    __syncthreads();

    // thread handles nodes i0, i0+1; wave covers 128 consecutive nodes/iter.
    // lane 0 has the smallest i0 in the wave -> __any == lane-0-valid.
    for (int i0 = cstart + tid * 2; __any(i0 < cend); i0 += BLOCK * 2) {
        bool v0 = (i0 < cend);
        bool v1 = (i0 + 1 < cend);
        float la = 0.0f, lb = 0.0f;
        int offa = -1, offb = -2;
        if (v0) {
            const float4* lg = reinterpret_cast<const float4*>(logits) + (size_t)i0 * 2;
            float4 a0 = lg[0];
            float4 a1 = lg[1];
            float4 b0, b1;
            int ta, tb = 0;
            if (v1) {
                b0 = lg[2];
                b1 = lg[3];
                int2 tt = *reinterpret_cast<const int2*>(targets + i0);  // i0 even
                int2 cc = *reinterpret_cast<const int2*>(cid + i0);
                ta = tt.x; tb = tt.y;
                offa = cc.x - base;
                offb = cc.y - base;
            } else {
                ta = targets[i0];
                offa = cid[i0] - base;
            }
            la = node_focal(a0, a1, ta);
            if (v1) lb = node_focal(b0, b1, tb);
        }

        int u = __shfl(offa, 0);
        bool uniform = __all(offa == u && offb == u) && (u < LDS_CAP);
        if (uniform) {
            // all 128 nodes in one segment: pair-combine then one butterfly
            float tsum = la + lb;
            float tmax = fmaxf(la, lb);
            #pragma unroll
            for (int o = 32; o > 0; o >>= 1) {
                tsum += __shfl_xor(tsum, o);
                tmax = fmaxf(tmax, __shfl_xor(tmax, o));
            }
            if (lane == 0) {
                atomicAdd(&lsum[u], tsum);
                atomicMax(&lmax[u], __float_as_int(tmax));
            }
        } else {
            if (v0) {
                if (offa < LDS_CAP) {
                    atomicAdd(&lsum[offa], la);
                    atomicMax(&lmax[offa], __float_as_int(la));
                } else {  // pathological window overflow
                    atomicAdd(&seg_sum[base + offa], la);
                    atomicMax(&seg_max_bits[base + offa], __float_as_int(la));
                }
            }
            if (v1) {
                if (offb < LDS_CAP) {
                    atomicAdd(&lsum[offb], lb);
                    atomicMax(&lmax[offb], __float_as_int(lb));
                } else {
                    atomicAdd(&seg_sum[base + offb], lb);
                    atomicMax(&seg_max_bits[base + offb], __float_as_int(lb));
                }
            }
        }
    }
    __syncthreads();

    // flush touched window entries: ~5-10 global atomic pairs per block
    for (int j = tid; j < LDS_CAP; j += BLOCK) {
        int mb = lmax[j];
        if (mb != (int)NEG_INF_BITS) {
            atomicAdd(&seg_sum[base + j], lsum[j]);
            atomicMax(&seg_max_bits[base + j], mb);
        }
    }
}

// ---------------------------------------------------------------------------
// Kernel 2: reduce K segments -> scalar
// ---------------------------------------------------------------------------
__global__ __launch_bounds__(256) void finalize_kernel(
        const float* __restrict__ seg_sum,
        const int* __restrict__ seg_max_bits,
        float* __restrict__ out) {
    __shared__ float s_acc[4];
    __shared__ float s_cnt[4];

    float acc = 0.0f, cnt = 0.0f;
    for (int k = threadIdx.x; k < K_SEGS; k += blockDim.x) {
        int mb = seg_max_bits[k];
        if (mb != (int)NEG_INF_BITS) {
            float mx = __int_as_float(mb);
            acc += ALPHA_W * seg_sum[k] + (1.0f - ALPHA_W) * mx;
            cnt += 1.0f;
        }
    }
    #pragma unroll
    for (int o = 32; o > 0; o >>= 1) {
        acc += __shfl_xor(acc, o);
        cnt += __shfl_xor(cnt, o);
    }
    int wid = threadIdx.x >> 6;
    if ((threadIdx.x & 63) == 0) { s_acc[wid] = acc; s_cnt[wid] = cnt; }
    __syncthreads();
    if (threadIdx.x == 0) {
        float a = s_acc[0] + s_acc[1] + s_acc[2] + s_acc[3];
        float c = s_cnt[0] + s_cnt[1] + s_cnt[2] + s_cnt[3];
        out[0] = a / fmaxf(c, 1.0f);
    }
}

// ---------------------------------------------------------------------------
extern "C" void kernel_launch(void* const* d_in, const int* in_sizes, int n_in,
                              void* d_out, int out_size, void* d_ws, size_t ws_size,
                              hipStream_t stream) {
    const float* logits = (const float*)d_in[0];
    const int* targets  = (const int*)d_in[1];
    const int* cid      = (const int*)d_in[2];
    float* out          = (float*)d_out;

    const int n = in_sizes[1];   // N = 4,000,000

    float* seg_sum    = (float*)d_ws;
    int* seg_max_bits = (int*)((char*)d_ws + K_SEGS * sizeof(float));

    init_ws_kernel<<<K_SEGS / 256, 256, 0, stream>>>(seg_sum, seg_max_bits);

    node_loss_kernel<<<NBLOCKS, BLOCK, 0, stream>>>(logits, targets, cid,
                                                    seg_sum, seg_max_bits, n);

    finalize_kernel<<<1, 256, 0, stream>>>(seg_sum, seg_max_bits, out);
}